// Round 1
// baseline (384.278 us; speedup 1.0000x reference)
//
#include <hip/hip_runtime.h>

typedef __bf16 bf16x8 __attribute__((ext_vector_type(8)));
typedef float floatx4 __attribute__((ext_vector_type(4)));
typedef unsigned short ushort8 __attribute__((ext_vector_type(8)));

__device__ __forceinline__ unsigned short f2bf(float f) {
    unsigned u = __float_as_uint(f);
    u += 0x7fffu + ((u >> 16) & 1u);   // round-to-nearest-even
    return (unsigned short)(u >> 16);
}

// ---------------------------------------------------------------------------
// K0: prep — transpose head_w2 [128][1296] fp32 -> w2t [1296][128] bf16,
//     and precompute the 18 Rot matrices (uniform across batch) into umat.
// ---------------------------------------------------------------------------
__global__ void prep_kernel(const float* __restrict__ w2, const float* __restrict__ qw,
                            unsigned short* __restrict__ w2t, float* __restrict__ umat) {
    int t = blockIdx.x * 256 + threadIdx.x;
    if (t < 18) {
        // PennyLane Rot = RZ(omega) RY(theta) RZ(phi):
        // U = [[ep*c, -conj(em)*s],[em*s, conj(ep)*c]],
        //   ep = e^{-i(phi+omega)/2}, em = e^{-i(phi-omega)/2}
        float phi = qw[t * 3], theta = qw[t * 3 + 1], omega = qw[t * 3 + 2];
        float c = cosf(0.5f * theta), s = sinf(0.5f * theta);
        float po = 0.5f * (phi + omega), pm = 0.5f * (phi - omega);
        float epr = cosf(po), epi = -sinf(po);
        float emr = cosf(pm), emi = -sinf(pm);
        float* u = umat + t * 8;
        u[0] = epr * c;  u[1] = epi * c;     // u00
        u[2] = -emr * s; u[3] = emi * s;     // u01 = -conj(em)*s
        u[4] = emr * s;  u[5] = emi * s;     // u10
        u[6] = epr * c;  u[7] = -epi * c;    // u11 = conj(ep)*c
    }
    if (t < 128 * 1296) {
        int nn = t >> 7, kk = t & 127;
        w2t[t] = f2bf(w2[kk * 1296 + nn]);
    }
}

// ---------------------------------------------------------------------------
// K1: encoder — angles = tanh(x@W1+b1)@W2+b2.
// Block = 256 thr = 4 waves; block handles 64 rows; wave w takes k-range
// [w*128, w*128+128) (split-K). W1 accessed at wave-uniform addresses ->
// scalar loads. Partials reduced through LDS.
// ---------------------------------------------------------------------------
__global__ __launch_bounds__(256) void enc_kernel(
    const float* __restrict__ x, const float* __restrict__ w1,
    const float* __restrict__ b1, const float* __restrict__ w2,
    const float* __restrict__ b2, float* __restrict__ angles) {
    __shared__ float part[4][64][33];  // +1 pad: conflict-free
    __shared__ float hsh[64][33];
    int lane = threadIdx.x & 63;
    int wave = threadIdx.x >> 6;
    int swave = __builtin_amdgcn_readfirstlane(wave);
    size_t row = (size_t)blockIdx.x * 64 + lane;
    const float4* x4 = (const float4*)(x + row * 512 + swave * 128);
    const float* wbase = w1 + swave * 128 * 32;  // uniform -> s_load

    float acc[32];
#pragma unroll
    for (int j = 0; j < 32; ++j) acc[j] = 0.f;
#pragma unroll 2
    for (int k4 = 0; k4 < 32; ++k4) {
        float4 xv = x4[k4];
        const float* wr = wbase + k4 * 128;
#pragma unroll
        for (int j = 0; j < 32; ++j) acc[j] += xv.x * wr[j];
#pragma unroll
        for (int j = 0; j < 32; ++j) acc[j] += xv.y * wr[32 + j];
#pragma unroll
        for (int j = 0; j < 32; ++j) acc[j] += xv.z * wr[64 + j];
#pragma unroll
        for (int j = 0; j < 32; ++j) acc[j] += xv.w * wr[96 + j];
    }
#pragma unroll
    for (int j = 0; j < 32; ++j) part[wave][lane][j] = acc[j];
    __syncthreads();

    // reduce partials + bias + tanh: thread (rl, jg) covers row rl, 8 j's
    int rl = threadIdx.x & 63;
    int jg = (threadIdx.x >> 6) * 8;
#pragma unroll
    for (int jj = 0; jj < 8; ++jj) {
        int j = jg + jj;
        float v = part[0][rl][j] + part[1][rl][j] + part[2][rl][j] + part[3][rl][j] + b1[j];
        hsh[rl][j] = tanhf(v);
    }
    __syncthreads();

    if (threadIdx.x < 64) {
        float h[32];
#pragma unroll
        for (int j = 0; j < 32; ++j) h[j] = hsh[threadIdx.x][j];
#pragma unroll
        for (int q = 0; q < 6; ++q) {
            float a = b2[q];
#pragma unroll
            for (int j = 0; j < 32; ++j) a += h[j] * w2[j * 6 + q];
            angles[((size_t)blockIdx.x * 64 + threadIdx.x) * 6 + q] = a;
        }
    }
}

// ---------------------------------------------------------------------------
// K2: quantum circuit, one sample per thread, state in registers.
// Qubit q has bit 1<<(5-q). Per layer, RY(data) and Rot(trained) on the same
// qubit are merged into one complex 2x2 (gates on distinct qubits commute).
// Fused epilogue: z -> g = relu(z@hw1+hb1) stored as bf16.
// ---------------------------------------------------------------------------
template <int ST>
__device__ __forceinline__ void apply_g(float* sr, float* si,
    float m00r, float m00i, float m01r, float m01i,
    float m10r, float m10i, float m11r, float m11i) {
#pragma unroll
    for (int i = 0; i < 64; ++i) {
        if ((i & ST) == 0) {
            int i1 = i + ST;
            float r0 = sr[i], u0 = si[i], r1 = sr[i1], u1 = si[i1];
            sr[i]  = m00r * r0 - m00i * u0 + m01r * r1 - m01i * u1;
            si[i]  = m00r * u0 + m00i * r0 + m01r * u1 + m01i * r1;
            sr[i1] = m10r * r0 - m10i * u0 + m11r * r1 - m11i * u1;
            si[i1] = m10r * u0 + m10i * r0 + m11r * u1 + m11i * r1;
        }
    }
}

template <int CB, int TB>
__device__ __forceinline__ void cnot_g(float* sr, float* si) {
#pragma unroll
    for (int i = 0; i < 64; ++i) {
        if ((i & CB) && !(i & TB)) {  // control set, target clear: swap pair
            int i1 = i + TB;
            float tr = sr[i]; sr[i] = sr[i1]; sr[i1] = tr;
            float ti = si[i]; si[i] = si[i1]; si[i1] = ti;
        }
    }
}

__global__ __launch_bounds__(64) void quantum_kernel(
    const float* __restrict__ angles, const float* __restrict__ umat,
    const float* __restrict__ hw1, const float* __restrict__ hb1,
    unsigned short* __restrict__ g) {
    int s = blockIdx.x * 64 + threadIdx.x;
    float ca[6], sa[6];
#pragma unroll
    for (int q = 0; q < 6; ++q) {
        float a = 0.5f * angles[(size_t)s * 6 + q];
        ca[q] = cosf(a);
        sa[q] = sinf(a);
    }
    float sr[64], si[64];
#pragma unroll
    for (int i = 0; i < 64; ++i) { sr[i] = 0.f; si[i] = 0.f; }
    sr[0] = 1.f;

#pragma clang loop unroll(disable)  // keep code ~1 layer for I-cache
    for (int layer = 0; layer < 3; ++layer) {
        const float* ub = umat + layer * 48;
        // M = U_rot * RY(a):  col0 = u0*c + u1*s ; col1 = -u0*s + u1*c
#define DOQ(Q, ST) {                                                      \
        const float* u = ub + (Q) * 8;                                    \
        float c = ca[Q], ss = sa[Q];                                      \
        float m00r = u[0] * c + u[2] * ss, m00i = u[1] * c + u[3] * ss;   \
        float m01r = u[2] * c - u[0] * ss, m01i = u[3] * c - u[1] * ss;   \
        float m10r = u[4] * c + u[6] * ss, m10i = u[5] * c + u[7] * ss;   \
        float m11r = u[6] * c - u[4] * ss, m11i = u[7] * c - u[5] * ss;   \
        apply_g<ST>(sr, si, m00r, m00i, m01r, m01i, m10r, m10i, m11r, m11i); }
        DOQ(0, 32) DOQ(1, 16) DOQ(2, 8) DOQ(3, 4) DOQ(4, 2) DOQ(5, 1)
#undef DOQ
        cnot_g<32, 16>(sr, si);  // CNOT(0,1)
        cnot_g<8, 4>(sr, si);    // CNOT(2,3)
        cnot_g<2, 1>(sr, si);    // CNOT(4,5)
        cnot_g<16, 8>(sr, si);   // CNOT(1,2)
        cnot_g<4, 2>(sr, si);    // CNOT(3,4)
        cnot_g<1, 32>(sr, si);   // CNOT(5,0)
    }

    float z[6] = {0.f, 0.f, 0.f, 0.f, 0.f, 0.f};
#pragma unroll
    for (int i = 0; i < 64; ++i) {
        float p = sr[i] * sr[i] + si[i] * si[i];
        z[0] += (i & 32) ? -p : p;
        z[1] += (i & 16) ? -p : p;
        z[2] += (i & 8)  ? -p : p;
        z[3] += (i & 4)  ? -p : p;
        z[4] += (i & 2)  ? -p : p;
        z[5] += (i & 1)  ? -p : p;
    }

    // g = relu(z @ hw1 + hb1), bf16
    unsigned short* gp = g + (size_t)s * 128;
#pragma unroll 2
    for (int j0 = 0; j0 < 128; j0 += 8) {
        ushort8 pk;
#pragma unroll
        for (int jj = 0; jj < 8; ++jj) {
            int j = j0 + jj;
            float a = hb1[j];
#pragma unroll
            for (int q = 0; q < 6; ++q) a += z[q] * hw1[q * 128 + j];
            a = fmaxf(a, 0.f);
            pk[jj] = f2bf(a);
        }
        *(ushort8*)(gp + j0) = pk;
    }
}

// ---------------------------------------------------------------------------
// K3: head GEMM — out[32768][1296] = g[32768][128]bf16 @ w2t[1296][128]bf16^T
//                + b2, fp32 out. MFMA 16x16x32 bf16, K=128 = 4 k-steps.
// Wave tile: M=64 (4 subtiles) x N=16. Tasks m-major (n fastest) so g and
// w2t stay L2-resident. A-frag: lane l holds A[m=l&15][k=(l>>4)*8+j] -> 16B
// contiguous from g. B-frag mirrors with n=l&15 -> 16B contiguous from w2t.
// C/D: col=lane&15, row=(lane>>4)*4+reg.
// ---------------------------------------------------------------------------
__global__ __launch_bounds__(256) void head_gemm(
    const unsigned short* __restrict__ g, const unsigned short* __restrict__ w2t,
    const float* __restrict__ b2, float* __restrict__ out) {
    int lane = threadIdx.x & 63;
    int task = blockIdx.x * 4 + (threadIdx.x >> 6);  // 41472 = 512*81 tasks
    int m = task / 81;      // 64-row group
    int n = task - m * 81;  // 16-col tile
    int row0 = m * 64, col0 = n * 16;
    int l15 = lane & 15, quad = lane >> 4;

    const unsigned short* bp = w2t + (size_t)(col0 + l15) * 128 + quad * 8;
    const unsigned short* ap = g + (size_t)(row0 + l15) * 128 + quad * 8;

    floatx4 acc[4];
#pragma unroll
    for (int t = 0; t < 4; ++t) acc[t] = (floatx4)0.f;

#pragma unroll
    for (int ks = 0; ks < 4; ++ks) {
        bf16x8 bf = *(const bf16x8*)(bp + ks * 32);
#pragma unroll
        for (int sub = 0; sub < 4; ++sub) {
            bf16x8 af = *(const bf16x8*)(ap + sub * 16 * 128 + ks * 32);
            acc[sub] = __builtin_amdgcn_mfma_f32_16x16x32_bf16(af, bf, acc[sub], 0, 0, 0);
        }
    }

    float bias = b2[col0 + l15];
#pragma unroll
    for (int sub = 0; sub < 4; ++sub) {
#pragma unroll
        for (int i = 0; i < 4; ++i) {
            int r = row0 + sub * 16 + quad * 4 + i;
            out[(size_t)r * 1296 + col0 + l15] = acc[sub][i] + bias;
        }
    }
}

// ---------------------------------------------------------------------------
extern "C" void kernel_launch(void* const* d_in, const int* in_sizes, int n_in,
                              void* d_out, int out_size, void* d_ws, size_t ws_size,
                              hipStream_t stream) {
    const float* x   = (const float*)d_in[0];
    const float* ew1 = (const float*)d_in[1];
    const float* eb1 = (const float*)d_in[2];
    const float* ew2 = (const float*)d_in[3];
    const float* eb2 = (const float*)d_in[4];
    const float* qw  = (const float*)d_in[5];
    const float* hw1 = (const float*)d_in[6];
    const float* hb1 = (const float*)d_in[7];
    const float* hw2 = (const float*)d_in[8];
    const float* hb2 = (const float*)d_in[9];
    float* out = (float*)d_out;

    char* ws = (char*)d_ws;
    unsigned short* g   = (unsigned short*)(ws);             // 32768*128*2 = 8388608 B
    unsigned short* w2t = (unsigned short*)(ws + 8388608);   // 1296*128*2  = 331776 B
    float* angles       = (float*)(ws + 8720384);            // 32768*6*4   = 786432 B
    float* umat         = (float*)(ws + 9506816);            // 18*8*4      = 576 B

    prep_kernel<<<dim3(648), dim3(256), 0, stream>>>(hw2, qw, w2t, umat);
    enc_kernel<<<dim3(512), dim3(256), 0, stream>>>(x, ew1, eb1, ew2, eb2, angles);
    quantum_kernel<<<dim3(512), dim3(64), 0, stream>>>(angles, umat, hw1, hb1, g);
    head_gemm<<<dim3(10368), dim3(256), 0, stream>>>(g, w2t, hb2, out);
}

// Round 3
// 318.916 us; speedup vs baseline: 1.2049x; 1.2049x over previous
//
#include <hip/hip_runtime.h>

typedef __bf16 bf16x8 __attribute__((ext_vector_type(8)));
typedef float floatx4 __attribute__((ext_vector_type(4)));
typedef unsigned short ushort8 __attribute__((ext_vector_type(8)));

__device__ __forceinline__ unsigned short f2bf(float f) {
    unsigned u = __float_as_uint(f);
    u += 0x7fffu + ((u >> 16) & 1u);   // round-to-nearest-even
    return (unsigned short)(u >> 16);
}

// ---------------------------------------------------------------------------
// K0: prep — transpose head_w2 [128][1296] fp32 -> w2t [1296][128] bf16
//     (8 kk per thread -> one ushort8 store), plus the 18 Rot matrices.
// ---------------------------------------------------------------------------
__global__ __launch_bounds__(256) void prep_kernel(
    const float* __restrict__ w2, const float* __restrict__ qw,
    unsigned short* __restrict__ w2t, float* __restrict__ umat) {
    int t = blockIdx.x * 256 + threadIdx.x;   // 81 blocks * 256 = 20736 threads
    if (t < 18) {
        // PennyLane Rot = RZ(omega) RY(theta) RZ(phi)
        float phi = qw[t * 3], theta = qw[t * 3 + 1], omega = qw[t * 3 + 2];
        float c = cosf(0.5f * theta), s = sinf(0.5f * theta);
        float po = 0.5f * (phi + omega), pm = 0.5f * (phi - omega);
        float epr = cosf(po), epi = -sinf(po);
        float emr = cosf(pm), emi = -sinf(pm);
        float* u = umat + t * 8;
        u[0] = epr * c;  u[1] = epi * c;     // u00
        u[2] = -emr * s; u[3] = emi * s;     // u01 = -conj(em)*s
        u[4] = emr * s;  u[5] = emi * s;     // u10
        u[6] = epr * c;  u[7] = -epi * c;    // u11 = conj(ep)*c
    }
    int nn = t >> 4;
    int kc = (t & 15) * 8;
    if (nn < 1296) {
        ushort8 pk;
#pragma unroll
        for (int j = 0; j < 8; ++j) pk[j] = f2bf(w2[(size_t)(kc + j) * 1296 + nn]);
        *(ushort8*)(w2t + (size_t)nn * 128 + kc) = pk;
    }
}

// ---------------------------------------------------------------------------
// K1: encoder — angles = tanh(x@W1+b1)@W2+b2.
// Block 256 = 4 waves; block handles 64 rows (lane = row); wave w owns
// k-range [w*128, w*128+128) (split-K). W1 addresses are wave-uniform ->
// s_load; k2-loop kept rolled so only 64 scalar floats live per iter
// (fits the ~102-SGPR budget; the R1 version needed 256 -> demoted to VMEM).
// ---------------------------------------------------------------------------
__global__ __launch_bounds__(256) void enc_kernel(
    const float* __restrict__ x, const float* __restrict__ w1,
    const float* __restrict__ b1, const float* __restrict__ w2,
    const float* __restrict__ b2, float* __restrict__ angles) {
    __shared__ float part[4][64][33];  // +1 pad: conflict-free
    __shared__ float hsh[64][33];
    int lane = threadIdx.x & 63;
    int wave = threadIdx.x >> 6;
    int swave = __builtin_amdgcn_readfirstlane(wave);
    size_t row = (size_t)blockIdx.x * 64 + lane;
    const float2* x2 = (const float2*)(x + row * 512 + swave * 128);
    const float* wseg = w1 + swave * 128 * 32;  // wave-uniform -> scalar

    float acc[32];
#pragma unroll
    for (int j = 0; j < 32; ++j) acc[j] = 0.f;

#pragma clang loop unroll(disable)
    for (int k2 = 0; k2 < 64; ++k2) {
        float2 xv = x2[k2];
        const float* wr = wseg + k2 * 64;
#pragma unroll
        for (int j = 0; j < 32; ++j) acc[j] = fmaf(wr[j], xv.x, acc[j]);
#pragma unroll
        for (int j = 0; j < 32; ++j) acc[j] = fmaf(wr[32 + j], xv.y, acc[j]);
    }
#pragma unroll
    for (int j = 0; j < 32; ++j) part[wave][lane][j] = acc[j];
    __syncthreads();

    // reduce partials + bias + tanh
    int rl = threadIdx.x & 63;
    int jg = (threadIdx.x >> 6) * 8;
#pragma unroll
    for (int jj = 0; jj < 8; ++jj) {
        int j = jg + jj;
        float v = part[0][rl][j] + part[1][rl][j] + part[2][rl][j] + part[3][rl][j] + b1[j];
        hsh[rl][j] = tanhf(v);
    }
    __syncthreads();

    if (threadIdx.x < 64) {
        float h[32];
#pragma unroll
        for (int j = 0; j < 32; ++j) h[j] = hsh[threadIdx.x][j];
#pragma unroll
        for (int q = 0; q < 6; ++q) {
            float a = b2[q];
#pragma unroll
            for (int j = 0; j < 32; ++j) a = fmaf(h[j], w2[j * 6 + q], a);
            angles[((size_t)blockIdx.x * 64 + threadIdx.x) * 6 + q] = a;
        }
    }
}

// ---------------------------------------------------------------------------
// K2: quantum circuit, one sample per thread, state in registers.
// ---------------------------------------------------------------------------
template <int ST>
__device__ __forceinline__ void apply_g(float* sr, float* si,
    float m00r, float m00i, float m01r, float m01i,
    float m10r, float m10i, float m11r, float m11i) {
#pragma unroll
    for (int i = 0; i < 64; ++i) {
        if ((i & ST) == 0) {
            int i1 = i + ST;
            float r0 = sr[i], u0 = si[i], r1 = sr[i1], u1 = si[i1];
            sr[i]  = m00r * r0 - m00i * u0 + m01r * r1 - m01i * u1;
            si[i]  = m00r * u0 + m00i * r0 + m01r * u1 + m01i * r1;
            sr[i1] = m10r * r0 - m10i * u0 + m11r * r1 - m11i * u1;
            si[i1] = m10r * u0 + m10i * r0 + m11r * u1 + m11i * r1;
        }
    }
}

template <int CB, int TB>
__device__ __forceinline__ void cnot_g(float* sr, float* si) {
#pragma unroll
    for (int i = 0; i < 64; ++i) {
        if ((i & CB) && !(i & TB)) {
            int i1 = i + TB;
            float tr = sr[i]; sr[i] = sr[i1]; sr[i1] = tr;
            float ti = si[i]; si[i] = si[i1]; si[i1] = ti;
        }
    }
}

__global__ __launch_bounds__(64) void quantum_kernel(
    const float* __restrict__ angles, const float* __restrict__ umat,
    const float* __restrict__ hw1, const float* __restrict__ hb1,
    unsigned short* __restrict__ g) {
    int s = blockIdx.x * 64 + threadIdx.x;
    float ca[6], sa[6];
#pragma unroll
    for (int q = 0; q < 6; ++q) {
        float a = 0.5f * angles[(size_t)s * 6 + q];
        ca[q] = cosf(a);
        sa[q] = sinf(a);
    }
    float sr[64], si[64];
#pragma unroll
    for (int i = 0; i < 64; ++i) { sr[i] = 0.f; si[i] = 0.f; }
    sr[0] = 1.f;

#pragma clang loop unroll(disable)
    for (int layer = 0; layer < 3; ++layer) {
        const float* ub = umat + layer * 48;
#define DOQ(Q, ST) {                                                      \
        const float* u = ub + (Q) * 8;                                    \
        float c = ca[Q], ss = sa[Q];                                      \
        float m00r = u[0] * c + u[2] * ss, m00i = u[1] * c + u[3] * ss;   \
        float m01r = u[2] * c - u[0] * ss, m01i = u[3] * c - u[1] * ss;   \
        float m10r = u[4] * c + u[6] * ss, m10i = u[5] * c + u[7] * ss;   \
        float m11r = u[6] * c - u[4] * ss, m11i = u[7] * c - u[5] * ss;   \
        apply_g<ST>(sr, si, m00r, m00i, m01r, m01i, m10r, m10i, m11r, m11i); }
        DOQ(0, 32) DOQ(1, 16) DOQ(2, 8) DOQ(3, 4) DOQ(4, 2) DOQ(5, 1)
#undef DOQ
        cnot_g<32, 16>(sr, si);  // CNOT(0,1)
        cnot_g<8, 4>(sr, si);    // CNOT(2,3)
        cnot_g<2, 1>(sr, si);    // CNOT(4,5)
        cnot_g<16, 8>(sr, si);   // CNOT(1,2)
        cnot_g<4, 2>(sr, si);    // CNOT(3,4)
        cnot_g<1, 32>(sr, si);   // CNOT(5,0)
    }

    float z[6] = {0.f, 0.f, 0.f, 0.f, 0.f, 0.f};
#pragma unroll
    for (int i = 0; i < 64; ++i) {
        float p = sr[i] * sr[i] + si[i] * si[i];
        z[0] += (i & 32) ? -p : p;
        z[1] += (i & 16) ? -p : p;
        z[2] += (i & 8)  ? -p : p;
        z[3] += (i & 4)  ? -p : p;
        z[4] += (i & 2)  ? -p : p;
        z[5] += (i & 1)  ? -p : p;
    }

    unsigned short* gp = g + (size_t)s * 128;
#pragma unroll 2
    for (int j0 = 0; j0 < 128; j0 += 8) {
        ushort8 pk;
#pragma unroll
        for (int jj = 0; jj < 8; ++jj) {
            int j = j0 + jj;
            float a = hb1[j];
#pragma unroll
            for (int q = 0; q < 6; ++q) a = fmaf(z[q], hw1[q * 128 + j], a);
            a = fmaxf(a, 0.f);
            pk[jj] = f2bf(a);
        }
        *(ushort8*)(gp + j0) = pk;
    }
}

// ---------------------------------------------------------------------------
// K3: head GEMM — out[32768][1296] = g@w2t^T + b2.
// A = w2t tile (M=16 output cols), B = g tile (N=16 batch rows). D layout:
// col=lane&15 -> batch row, row=quad*4+i -> output col, so each lane's 4 acc
// elements are 4 CONSECUTIVE output columns -> one nontemporal dwordx4 store.
// Wave tile: 48 cols (3 A-tiles) x 64 rows (4 B-subtiles) = 48 MFMA,
// 28 hoisted 16B loads, 12 float4 stores. 13824 waves (R1: 41472).
// ---------------------------------------------------------------------------
__global__ __launch_bounds__(256) void head_gemm(
    const unsigned short* __restrict__ g, const unsigned short* __restrict__ w2t,
    const float* __restrict__ b2, float* __restrict__ out) {
    int lane = threadIdx.x & 63;
    int task = blockIdx.x * 4 + (threadIdx.x >> 6);  // 13824 = 512 m * 27 n
    int m = task / 27;
    int n = task - m * 27;
    int row0 = m * 64, col0 = n * 48;
    int l15 = lane & 15, quad = lane >> 4;

    const unsigned short* ap = w2t + (size_t)(col0 + l15) * 128 + quad * 8;   // A: w2t
    const unsigned short* bp = g + (size_t)(row0 + l15) * 128 + quad * 8;     // B: g

    floatx4 acc[12];  // [t][sub]
#pragma unroll
    for (int i = 0; i < 12; ++i) acc[i] = (floatx4)0.f;

#pragma unroll
    for (int ks = 0; ks < 4; ++ks) {
        bf16x8 af[3], bf[4];
#pragma unroll
        for (int t = 0; t < 3; ++t) af[t] = *(const bf16x8*)(ap + (size_t)t * 16 * 128 + ks * 32);
#pragma unroll
        for (int sub = 0; sub < 4; ++sub) bf[sub] = *(const bf16x8*)(bp + (size_t)sub * 16 * 128 + ks * 32);
#pragma unroll
        for (int t = 0; t < 3; ++t)
#pragma unroll
            for (int sub = 0; sub < 4; ++sub)
                acc[t * 4 + sub] = __builtin_amdgcn_mfma_f32_16x16x32_bf16(af[t], bf[sub], acc[t * 4 + sub], 0, 0, 0);
    }

#pragma unroll
    for (int t = 0; t < 3; ++t) {
        const float* bb = b2 + col0 + t * 16 + quad * 4;
        floatx4 bias = { bb[0], bb[1], bb[2], bb[3] };
#pragma unroll
        for (int sub = 0; sub < 4; ++sub) {
            floatx4 v = acc[t * 4 + sub] + bias;
            floatx4* dst = (floatx4*)(out + (size_t)(row0 + sub * 16 + l15) * 1296 + col0 + t * 16 + quad * 4);
            __builtin_nontemporal_store(v, dst);
        }
    }
}

// ---------------------------------------------------------------------------
extern "C" void kernel_launch(void* const* d_in, const int* in_sizes, int n_in,
                              void* d_out, int out_size, void* d_ws, size_t ws_size,
                              hipStream_t stream) {
    const float* x   = (const float*)d_in[0];
    const float* ew1 = (const float*)d_in[1];
    const float* eb1 = (const float*)d_in[2];
    const float* ew2 = (const float*)d_in[3];
    const float* eb2 = (const float*)d_in[4];
    const float* qw  = (const float*)d_in[5];
    const float* hw1 = (const float*)d_in[6];
    const float* hb1 = (const float*)d_in[7];
    const float* hw2 = (const float*)d_in[8];
    const float* hb2 = (const float*)d_in[9];
    float* out = (float*)d_out;

    char* ws = (char*)d_ws;
    unsigned short* g   = (unsigned short*)(ws);             // 32768*128*2 = 8388608 B
    unsigned short* w2t = (unsigned short*)(ws + 8388608);   // 1296*128*2  = 331776 B
    float* angles       = (float*)(ws + 8720384);            // 32768*6*4   = 786432 B
    float* umat         = (float*)(ws + 9506816);            // 18*8*4      = 576 B

    prep_kernel<<<dim3(81), dim3(256), 0, stream>>>(hw2, qw, w2t, umat);
    enc_kernel<<<dim3(512), dim3(256), 0, stream>>>(x, ew1, eb1, ew2, eb2, angles);
    quantum_kernel<<<dim3(512), dim3(64), 0, stream>>>(angles, umat, hw1, hb1, g);
    head_gemm<<<dim3(3456), dim3(256), 0, stream>>>(g, w2t, hb2, out);
}